// Round 3
// baseline (1004.787 us; speedup 1.0000x reference)
//
#include <hip/hip_runtime.h>
#include <hip/hip_bf16.h>

#define N_   64
#define C4_  64
#define V_   25
#define T_   128
#define K_   3
#define OC_  192   // C4_*K_

// ---------------- K1: acc + depthwise temporal conv (5-tap, same pad) -------
// flat: each thread computes 4 consecutive t of one (n,c,v) row.
// grid = N_*C4_*V_*32 threads = 12800 blocks x 256
__global__ __launch_bounds__(256)
void k1_acc_conv(const float* __restrict__ x, const float* __restrict__ out,
                 const float* __restrict__ conv_w, const float* __restrict__ conv_b,
                 float* __restrict__ s, int branch) {
    int g = blockIdx.x * blockDim.x + threadIdx.x;  // 0 .. N*C4*V*32-1
    int t4 = (g & 31) * 4;
    int rest = g >> 5;
    int v  = rest % V_;
    int nc = rest / V_;
    int c  = nc % C4_;
    int n  = nc / C4_;

    const float* px = x   + ((size_t)(n * 256 + branch * C4_ + c) * V_ + v) * T_;
    const float* pz = out + ((size_t)(n * 256 + (branch - 1) * C4_ + c) * V_ + v) * T_;

    float a[8];
    #pragma unroll
    for (int u = 0; u < 8; ++u) {
        int tt = t4 + u - 2;
        float val = 0.f;
        if (tt >= 0 && tt < T_) {
            val = px[tt];
            if (branch > 0) val += pz[tt];
        }
        a[u] = val;
    }
    const float* wp = conv_w + (branch * C4_ + c) * 5;
    float w0 = wp[0], w1 = wp[1], w2 = wp[2], w3 = wp[3], w4 = wp[4];
    float b  = conv_b[branch * C4_ + c];
    float4 r;
    r.x = b + w0*a[0] + w1*a[1] + w2*a[2] + w3*a[3] + w4*a[4];
    r.y = b + w0*a[1] + w1*a[2] + w2*a[3] + w3*a[4] + w4*a[5];
    r.z = b + w0*a[2] + w1*a[3] + w2*a[4] + w3*a[5] + w4*a[6];
    r.w = b + w0*a[3] + w1*a[4] + w2*a[5] + w3*a[6] + w4*a[7];
    float* ps = s + ((size_t)(n * C4_ + c) * V_ + v) * T_ + t4;
    *(float4*)ps = r;
}

// ---------------- K23: fused per-node 1x1 conv + adjacency + BN + LeakyReLU -
// y[n,o,w,t] = sum_cin W[w,o,cin] * s[n,cin,w,t]   (o = c*3+k, used only by c)
// z[n,c,v,t] = sum_{k,w} A[k,w,v] * y[n,c*3+k,w,t] -> BN -> LeakyReLU -> out
// grid = N_*32 blocks (c-pair per block), 128 threads (t)
// launch_bounds(128,4): cap 128 VGPRs so acc[2][25]+yv[6] stay in VGPRs
// (round-2 build showed VGPR_Count=48 -> accs were bouncing through AGPR/scratch)
__global__ __launch_bounds__(128, 4)
void k23(const float* __restrict__ s, const float* __restrict__ gW,
         const float* __restrict__ A,
         const float* __restrict__ bng, const float* __restrict__ bnb,
         const float* __restrict__ bnm, const float* __restrict__ bnv,
         float* __restrict__ out, int branch) {
    int bid = blockIdx.x;
    int cg = bid % 32;           // c0 = cg*2
    int n  = bid / 32;
    int t  = threadIdx.x;

    float acc0[V_], acc1[V_];
    #pragma unroll
    for (int v = 0; v < V_; ++v) { acc0[v] = 0.f; acc1[v] = 0.f; }

    const float* sp = s + (size_t)n * C4_ * V_ * T_ + t;

    #pragma unroll 1
    for (int w = 0; w < V_; ++w) {
        float yv[6] = {0.f, 0.f, 0.f, 0.f, 0.f, 0.f};   // [cLocal*3 + k]
        const float* Wb = gW + (((size_t)branch * V_ + w) * OC_ + cg * 6) * C4_;
        const float* srow = sp + (size_t)w * T_;
        #pragma unroll 8
        for (int cin = 0; cin < C4_; ++cin) {
            float sv = srow[(size_t)cin * (V_ * T_)];
            #pragma unroll
            for (int j = 0; j < 6; ++j)
                yv[j] += Wb[(size_t)j * C4_ + cin] * sv;   // uniform -> s_load
        }
        #pragma unroll
        for (int k = 0; k < K_; ++k) {
            const float* Ap = A + (k * V_ + w) * V_;
            float y0 = yv[k], y1 = yv[3 + k];
            #pragma unroll
            for (int v = 0; v < V_; ++v) {
                float av = Ap[v];                          // uniform -> s_load
                acc0[v] += av * y0;
                acc1[v] += av * y1;
            }
        }
    }

    #pragma unroll
    for (int cl = 0; cl < 2; ++cl) {
        int c = cg * 2 + cl;
        float g  = bng[branch * C4_ + c];
        float be = bnb[branch * C4_ + c];
        float mu = bnm[branch * C4_ + c];
        float va = bnv[branch * C4_ + c];
        float sc = g * rsqrtf(va + 1e-5f);
        float* op = out + ((size_t)(n * 256 + branch * C4_ + c) * V_) * T_ + t;
        const float* accp = cl ? acc1 : acc0;
        #pragma unroll
        for (int v = 0; v < V_; ++v) {
            float val = (accp[v] - mu) * sc + be;
            val = val > 0.f ? val : 0.2f * val;
            op[(size_t)v * T_] = val;
        }
    }
}

// ---------------- K4: passthrough split[3] -> out channels 192..255 ---------
__global__ __launch_bounds__(256)
void k4_copy(const float* __restrict__ x, float* __restrict__ out) {
    int i = blockIdx.x * blockDim.x + threadIdx.x;   // 0 .. 3,276,799
    int n = i / 51200;
    int j = i % 51200;
    const float4* src = (const float4*)(x + (size_t)(n * 256 + 192) * (V_ * T_));
    float4* dst = (float4*)(out + (size_t)(n * 256 + 192) * (V_ * T_));
    dst[j] = src[j];
}

extern "C" void kernel_launch(void* const* d_in, const int* in_sizes, int n_in,
                              void* d_out, int out_size, void* d_ws, size_t ws_size,
                              hipStream_t stream) {
    const float* x      = (const float*)d_in[0];
    const float* A      = (const float*)d_in[1];
    const float* conv_w = (const float*)d_in[2];
    const float* conv_b = (const float*)d_in[3];
    const float* gW     = (const float*)d_in[4];
    const float* bng    = (const float*)d_in[5];
    const float* bnb    = (const float*)d_in[6];
    const float* bnm    = (const float*)d_in[7];
    const float* bnv    = (const float*)d_in[8];
    float* out = (float*)d_out;

    float* s = (float*)d_ws;   // N*C4*V*T fp32 = 52,428,800 B

    for (int i = 0; i < 3; ++i) {
        hipLaunchKernelGGL(k1_acc_conv, dim3(12800), dim3(256), 0, stream,
                           x, out, conv_w, conv_b, s, i);
        hipLaunchKernelGGL(k23, dim3(N_ * 32), dim3(T_), 0, stream,
                           s, gW, A, bng, bnb, bnm, bnv, out, i);
    }
    hipLaunchKernelGGL(k4_copy, dim3(12800), dim3(256), 0, stream, x, out);
}